// Round 2
// baseline (169.640 us; speedup 1.0000x reference)
//
#include <hip/hip_runtime.h>
#include <hip/hip_cooperative_groups.h>
#include <math.h>

namespace cg = cooperative_groups;

#define N 512
#define D 512
#define NC 10
#define EPSF 1e-8f

typedef __attribute__((ext_vector_type(8))) __bf16 bf16x8;
typedef __attribute__((ext_vector_type(4))) float f32x4;

__device__ __forceinline__ unsigned short f2bf_rne(float f) {
  unsigned u = __float_as_uint(f);
  u += 0x7fffu + ((u >> 16) & 1u);
  return (unsigned short)(u >> 16);
}
__device__ __forceinline__ float bf2f(unsigned short h) {
  return __uint_as_float(((unsigned)h) << 16);
}

// One cooperative kernel, 256 blocks x 256 threads, 3 phases:
//  P1: fp32->bf16 hi/lo split (2 rows/block) + fp32 row norms + class_pos
//  P2: Gram via bf16-split MFMA (verbatim round-1 code; 32x32 tile/block)
//  P3: per-row loss (2 rows/block), atomicAdd into out
__global__ __launch_bounds__(256) void k_all(
    const float* __restrict__ pred, const float* __restrict__ dist_raw,
    const int* __restrict__ target,
    unsigned short* __restrict__ XH, unsigned short* __restrict__ XL,
    float* __restrict__ G, float* __restrict__ inv_n,
    float* __restrict__ class_pos, float* __restrict__ out) {
  __shared__ __align__(16) unsigned char smraw[4 * 32 * 256 * 2];  // 64 KiB

  const int tid = threadIdx.x;
  const int bid = blockIdx.x;
  const int lane = tid & 63;
  const int wid = tid >> 6;
  cg::grid_group grid = cg::this_grid();

  // ---------------- Phase 1: convert + norms ----------------
  {
    const int row = bid * 2 + (tid >> 7);  // 128 threads per row
    const int c4 = tid & 127;              // float4 index within row
    float4 v = ((const float4*)(pred + (size_t)row * D))[c4];
    ushort4 h, l;
    h.x = f2bf_rne(v.x); l.x = f2bf_rne(v.x - bf2f(h.x));
    h.y = f2bf_rne(v.y); l.y = f2bf_rne(v.y - bf2f(h.y));
    h.z = f2bf_rne(v.z); l.z = f2bf_rne(v.z - bf2f(h.z));
    h.w = f2bf_rne(v.w); l.w = f2bf_rne(v.w - bf2f(h.w));
    ((ushort4*)(XH + (size_t)row * D))[c4] = h;
    ((ushort4*)(XL + (size_t)row * D))[c4] = l;

    float p = v.x * v.x + v.y * v.y + v.z * v.z + v.w * v.w;
#pragma unroll
    for (int off = 32; off > 0; off >>= 1) p += __shfl_down(p, off);
    float* wsum = (float*)smraw;
    if (lane == 0) wsum[wid] = p;
    __syncthreads();
    if (tid == 0) {
      inv_n[bid * 2]     = 1.0f / fmaxf(sqrtf(wsum[0] + wsum[1]), EPSF);
      inv_n[bid * 2 + 1] = 1.0f / fmaxf(sqrtf(wsum[2] + wsum[3]), EPSF);
    }
    if (bid == 0 && tid == 64) {  // a different wave: class_pos + out=0
      out[0] = 0.0f;  // d_out poisoned each launch; P3 accumulates
      float acc = 0.0f;
      class_pos[0] = 0.0f;
      for (int c = 0; c < NC - 1; ++c) {
        acc += log1pf(expf(dist_raw[c]));
        class_pos[c + 1] = acc;
      }
    }
    __syncthreads();  // wsum reads done before P2 overwrites smraw
  }
  __threadfence();
  grid.sync();

  // ---------------- Phase 2: Gram MFMA (round-1 proven code) ----------------
  {
    typedef unsigned short LBrow[32][256];
    LBrow* LB = (LBrow*)smraw;  // [4][32][256] bf16 = 64 KiB
    const int bi = bid >> 4, bj = bid & 15;

    const unsigned short* __restrict__ srcArr = (wid & 1) ? XL : XH;
    const int tileBase = ((wid < 2) ? bi : bj) * 32;

    const int frow = lane & 15;
    const int kg = lane >> 4;  // 0..3
    const int wr = wid >> 1, wc = wid & 1;
    const int arow = wr * 16 + frow;
    const int brow = wc * 16 + frow;

    f32x4 ahh = {0.f, 0.f, 0.f, 0.f};
    f32x4 ahl = ahh, alh = ahh, all_ = ahh;

    for (int c = 0; c < 2; ++c) {  // two K-chunks of 256
#pragma unroll
      for (int i = 0; i < 16; ++i) {
        const int gr = i * 64 + lane;
        const int row = gr >> 5;
        const int gsw = (lane & 31) ^ (row & 7);  // inverse-swizzled source
        const unsigned short* src =
            srcArr + (size_t)(tileBase + row) * D + c * 256 + gsw * 8;
        unsigned short* dst = &LB[wid][0][0] + (size_t)i * 64 * 8;  // uniform
        __builtin_amdgcn_global_load_lds(
            (const __attribute__((address_space(1))) void*)src,
            (__attribute__((address_space(3))) void*)dst, 16, 0, 0);
      }
      __syncthreads();  // vmcnt(0) drain + barrier
#pragma unroll
      for (int kc = 0; kc < 8; ++kc) {
        const int ga = ((kc * 4 + kg) ^ (arow & 7)) * 8;
        const int gb = ((kc * 4 + kg) ^ (brow & 7)) * 8;
        bf16x8 ah = *(const bf16x8*)&LB[0][arow][ga];
        bf16x8 al = *(const bf16x8*)&LB[1][arow][ga];
        bf16x8 bh = *(const bf16x8*)&LB[2][brow][gb];
        bf16x8 bl = *(const bf16x8*)&LB[3][brow][gb];
        ahh = __builtin_amdgcn_mfma_f32_16x16x32_bf16(ah, bh, ahh, 0, 0, 0);
        ahl = __builtin_amdgcn_mfma_f32_16x16x32_bf16(ah, bl, ahl, 0, 0, 0);
        alh = __builtin_amdgcn_mfma_f32_16x16x32_bf16(al, bh, alh, 0, 0, 0);
        all_ = __builtin_amdgcn_mfma_f32_16x16x32_bf16(al, bl, all_, 0, 0, 0);
      }
      __syncthreads();
    }

    // C/D: col = lane&15, row = (lane>>4)*4 + r   [m89-verified]
    const int gcol = bj * 32 + wc * 16 + frow;
    const int grow0 = bi * 32 + wr * 16 + kg * 4;
#pragma unroll
    for (int r = 0; r < 4; ++r) {
      G[(size_t)(grow0 + r) * N + gcol] = ahh[r] + all_[r] + (ahl[r] + alh[r]);
    }
  }
  __threadfence();
  grid.sync();

  // ---------------- Phase 3: per-row loss (2 rows/block) ----------------
  {
    float* s_p = (float*)smraw;                  // [512] compacted positives
    float* s_cp = (float*)(smraw + 2176);        // [16] class_pos
    int* s_np = (int*)(smraw + 2304);
    float* s_part = (float*)(smraw + 2368);      // [4]

    if (tid < NC) s_cp[tid] = class_pos[tid];

    for (int rr = 0; rr < 2; ++rr) {
      const int i = bid * 2 + rr;
      if (tid == 0) *s_np = 0;
      __syncthreads();

      const int ti = target[i];
      const float inv_i = inv_n[i];
      const float cpi = s_cp[ti];

      float a0, a1;
      {
        const int j = tid;
        const float cosv = G[(size_t)i * N + j] * inv_i * inv_n[j];
        const int tj = target[j];
        if (tj != ti) {
          a0 = cosv + fabsf(cpi - s_cp[tj]);
        } else {
          a0 = -1e30f;
          if (j != i) { int k = atomicAdd(s_np, 1); s_p[k] = cosv; }
        }
      }
      {
        const int j = tid + 256;
        const float cosv = G[(size_t)i * N + j] * inv_i * inv_n[j];
        const int tj = target[j];
        if (tj != ti) {
          a1 = cosv + fabsf(cpi - s_cp[tj]);
        } else {
          a1 = -1e30f;
          if (j != i) { int k = atomicAdd(s_np, 1); s_p[k] = cosv; }
        }
      }
      __syncthreads();

      const int np = *s_np;
      const int nn = N - 1 - np;
      float acc = 0.0f;
      for (int kk = 0; kk < np; ++kk) {
        const float ck = s_p[kk];  // LDS broadcast
        acc += fmaxf(a0 - ck, 0.0f) + fmaxf(a1 - ck, 0.0f);
      }

#pragma unroll
      for (int off = 32; off > 0; off >>= 1) acc += __shfl_down(acc, off);
      if (lane == 0) s_part[wid] = acc;
      __syncthreads();
      if (tid == 0) {
        const float total = s_part[0] + s_part[1] + s_part[2] + s_part[3];
        if (np > 0 && nn > 0) {
          atomicAdd(out, total / ((float)nn * (float)nn * (float)np) / (float)N);
        }
      }
      __syncthreads();  // protect s_p/s_np reuse by next row
    }
  }
}

extern "C" void kernel_launch(void* const* d_in, const int* in_sizes, int n_in,
                              void* d_out, int out_size, void* d_ws, size_t ws_size,
                              hipStream_t stream) {
  const float* pred = (const float*)d_in[0];
  const float* dist_raw = (const float*)d_in[1];
  const int* target = (const int*)d_in[2];
  float* out = (float*)d_out;

  float* G = (float*)d_ws;                                  // 1 MiB
  float* inv_n = G + (size_t)N * N;                         // 2 KiB
  float* class_pos = inv_n + N;                             // 64 B
  unsigned short* XH = (unsigned short*)(class_pos + 16);   // 512 KiB
  unsigned short* XL = XH + (size_t)N * D;                  // 512 KiB

  void* args[] = {(void*)&pred, (void*)&dist_raw, (void*)&target,
                  (void*)&XH,   (void*)&XL,       (void*)&G,
                  (void*)&inv_n, (void*)&class_pos, (void*)&out};
  hipLaunchCooperativeKernel((const void*)k_all, dim3(256), dim3(256), args, 0,
                             stream);
}

// Round 3
// 72.588 us; speedup vs baseline: 2.3370x; 2.3370x over previous
//
#include <hip/hip_runtime.h>
#include <math.h>

#define N 512
#define D 512
#define NC 10
#define EPSF 1e-8f

typedef __attribute__((ext_vector_type(8))) __bf16 bf16x8;
typedef __attribute__((ext_vector_type(4))) float f32x4;

// ---------------- Kernel 1: fused convert + Gram via bf16-split MFMA --------
// grid (16,16), block 256 (4 waves). 32x32 output tile per block, each wave one
// 16x16 quadrant. G = hi*hi^T + hi*lo^T + lo*hi^T + lo*lo^T.
// Staging is reg-staged from fp32: per chunk (K=256), waves 0-1 convert the
// A-tile (hi+lo), waves 2-3 the B-tile. 16B granule g of row r is stored at
// LDS position g ^ (r&7) (XOR swizzle); source address carries the inverse
// swizzle, ds_write is linear -> MFMA-phase reads are conflict-free and
// identical to the round-1 proven code. Chunk-1 fp32 loads issue before
// chunk-0 MFMA (latency hidden under compute).
__global__ __launch_bounds__(256) void k_gram(
    const float* __restrict__ pred, const float* __restrict__ dist_raw,
    float* __restrict__ G, float* __restrict__ inv_n,
    float* __restrict__ class_pos, float* __restrict__ out) {
  __shared__ unsigned short LB[4][32][256];  // 64 KiB: A_hi, A_lo, B_hi, B_lo

  const int t = threadIdx.x;
  const int lane = t & 63;
  const int wid = t >> 6;  // 0..3
  const int bi = blockIdx.y, bj = blockIdx.x;

  if (bi == 0 && bj == 0 && t == 0) {  // class_pos + out=0 (out poisoned/launch)
    out[0] = 0.0f;
    float acc = 0.0f;
    class_pos[0] = 0.0f;
    for (int c = 0; c < NC - 1; ++c) {
      acc += log1pf(expf(dist_raw[c]));
      class_pos[c + 1] = acc;
    }
  }

  const int p = wid >> 1;   // 0 = A-tile (bi), 1 = B-tile (bj)
  const int sub = wid & 1;  // which half of the 1024 granules this wave stages
  const int tileBase = (p ? bj : bi) * 32;

  // MFMA fragment addressing (round-1 verbatim)
  const int frow = lane & 15;
  const int kg = lane >> 4;  // 0..3
  const int wr = wid >> 1, wc = wid & 1;
  const int arow = wr * 16 + frow;
  const int brow = wc * 16 + frow;

  f32x4 ahh = {0.f, 0.f, 0.f, 0.f};
  f32x4 ahl = ahh, alh = ahh, all_ = ahh;

  float4 st[16];  // staged fp32 for the current chunk (2 float4 per iteration)

  // ---- issue chunk-0 fp32 loads ----
#pragma unroll
  for (int it = 0; it < 8; ++it) {
    const int gr = sub * 512 + it * 64 + lane;  // granule 0..1023 of this tile
    const int row = gr >> 5, gpos = gr & 31;
    const int glog = gpos ^ (row & 7);  // inverse swizzle on the SOURCE
    const float* s = pred + (size_t)(tileBase + row) * D + glog * 8;
    st[2 * it] = *(const float4*)(s);
    st[2 * it + 1] = *(const float4*)(s + 4);
  }

  for (int c = 0; c < 2; ++c) {  // two K-chunks of 256
    // convert + ds_write current chunk (linear position gpos)
#pragma unroll
    for (int it = 0; it < 8; ++it) {
      const int gr = sub * 512 + it * 64 + lane;
      const int row = gr >> 5, gpos = gr & 31;
      const float f[8] = {st[2 * it].x,     st[2 * it].y,     st[2 * it].z,
                          st[2 * it].w,     st[2 * it + 1].x, st[2 * it + 1].y,
                          st[2 * it + 1].z, st[2 * it + 1].w};
      bf16x8 hv, lv;
#pragma unroll
      for (int k = 0; k < 8; ++k) {
        const __bf16 h = (__bf16)f[k];
        hv[k] = h;
        lv[k] = (__bf16)(f[k] - (float)h);
      }
      *(bf16x8*)&LB[2 * p][row][gpos * 8] = hv;
      *(bf16x8*)&LB[2 * p + 1][row][gpos * 8] = lv;
    }
    __syncthreads();  // staging visible to all waves

    if (c == 0) {  // issue chunk-1 fp32 loads; they drain under chunk-0 MFMA
#pragma unroll
      for (int it = 0; it < 8; ++it) {
        const int gr = sub * 512 + it * 64 + lane;
        const int row = gr >> 5, gpos = gr & 31;
        const int glog = gpos ^ (row & 7);
        const float* s = pred + (size_t)(tileBase + row) * D + 256 + glog * 8;
        st[2 * it] = *(const float4*)(s);
        st[2 * it + 1] = *(const float4*)(s + 4);
      }
    }

#pragma unroll
    for (int kc = 0; kc < 8; ++kc) {
      const int ga = ((kc * 4 + kg) ^ (arow & 7)) * 8;
      const int gb = ((kc * 4 + kg) ^ (brow & 7)) * 8;
      bf16x8 ah = *(const bf16x8*)&LB[0][arow][ga];
      bf16x8 al = *(const bf16x8*)&LB[1][arow][ga];
      bf16x8 bh = *(const bf16x8*)&LB[2][brow][gb];
      bf16x8 bl = *(const bf16x8*)&LB[3][brow][gb];
      ahh = __builtin_amdgcn_mfma_f32_16x16x32_bf16(ah, bh, ahh, 0, 0, 0);
      ahl = __builtin_amdgcn_mfma_f32_16x16x32_bf16(ah, bl, ahl, 0, 0, 0);
      alh = __builtin_amdgcn_mfma_f32_16x16x32_bf16(al, bh, alh, 0, 0, 0);
      all_ = __builtin_amdgcn_mfma_f32_16x16x32_bf16(al, bl, all_, 0, 0, 0);
    }
    __syncthreads();  // reads done before next chunk overwrites LDS
  }

  // C/D: col = lane&15, row = (lane>>4)*4 + r   [m89-verified]
  const int gcol = bj * 32 + wc * 16 + frow;
  const int grow0 = bi * 32 + wr * 16 + kg * 4;
#pragma unroll
  for (int r = 0; r < 4; ++r) {
    const float v = ahh[r] + all_[r] + (ahl[r] + alh[r]);
    G[(size_t)(grow0 + r) * N + gcol] = v;
    if (bi == bj && (grow0 + r) == gcol)
      inv_n[gcol] = 1.0f / fmaxf(sqrtf(v), EPSF);
  }
}

// ---------------- Kernel 2: per-row loss + global mean (round-1 proven) -----
__global__ __launch_bounds__(256) void k_rows(
    const float* __restrict__ G, const int* __restrict__ target,
    const float* __restrict__ inv_n, const float* __restrict__ class_pos,
    float* __restrict__ out) {
  const int i = blockIdx.x;
  const int tid = threadIdx.x;

  __shared__ float s_p[N];
  __shared__ float s_cp[16];
  __shared__ int s_np;
  __shared__ float s_part[4];

  if (tid == 0) s_np = 0;
  if (tid < NC) s_cp[tid] = class_pos[tid];
  __syncthreads();

  const int ti = target[i];
  const float inv_i = inv_n[i];
  const float cpi = s_cp[ti];

  float a0, a1;
  {
    const int j = tid;
    const float cosv = G[(size_t)i * N + j] * inv_i * inv_n[j];
    const int tj = target[j];
    if (tj != ti) {
      a0 = cosv + fabsf(cpi - s_cp[tj]);
    } else {
      a0 = -1e30f;
      if (j != i) { int k = atomicAdd(&s_np, 1); s_p[k] = cosv; }
    }
  }
  {
    const int j = tid + 256;
    const float cosv = G[(size_t)i * N + j] * inv_i * inv_n[j];
    const int tj = target[j];
    if (tj != ti) {
      a1 = cosv + fabsf(cpi - s_cp[tj]);
    } else {
      a1 = -1e30f;
      if (j != i) { int k = atomicAdd(&s_np, 1); s_p[k] = cosv; }
    }
  }
  __syncthreads();

  const int np = s_np;
  const int nn = N - 1 - np;  // negatives = N - 1 - (positives)
  float acc = 0.0f;
  for (int kk = 0; kk < np; ++kk) {
    const float ck = s_p[kk];  // LDS broadcast
    acc += fmaxf(a0 - ck, 0.0f) + fmaxf(a1 - ck, 0.0f);
  }

#pragma unroll
  for (int off = 32; off > 0; off >>= 1) acc += __shfl_down(acc, off);
  if ((tid & 63) == 0) s_part[tid >> 6] = acc;
  __syncthreads();
  if (tid == 0) {
    const float total = s_part[0] + s_part[1] + s_part[2] + s_part[3];
    if (np > 0 && nn > 0) {
      atomicAdd(out, total / ((float)nn * (float)nn * (float)np) / (float)N);
    }
  }
}

extern "C" void kernel_launch(void* const* d_in, const int* in_sizes, int n_in,
                              void* d_out, int out_size, void* d_ws, size_t ws_size,
                              hipStream_t stream) {
  const float* pred = (const float*)d_in[0];
  const float* dist_raw = (const float*)d_in[1];
  const int* target = (const int*)d_in[2];
  float* out = (float*)d_out;

  float* G = (float*)d_ws;            // 1 MiB
  float* inv_n = G + (size_t)N * N;   // 2 KiB
  float* class_pos = inv_n + N;       // 64 B

  k_gram<<<dim3(16, 16), 256, 0, stream>>>(pred, dist_raw, G, inv_n, class_pos,
                                           out);
  k_rows<<<N, 256, 0, stream>>>(G, target, inv_n, class_pos, out);
}